// Round 1
// baseline (1526.667 us; speedup 1.0000x reference)
//
#include <hip/hip_runtime.h>
#include <stdint.h>

#define NPTS   4096
#define NPOINT 1024
#define NSAMP  32
#define NROWS  262144   // B*NPOINT*NSAMP
#define RAD2   0.04f

// ---------------------------------------------------------------------------
// FPS: one block per batch, bit-exact distance chain vs fp32 reference.
// ---------------------------------------------------------------------------
__global__ __launch_bounds__(256) void fps_kernel(const float* __restrict__ xyz,
                                                  float* __restrict__ outx,
                                                  int* __restrict__ fidx)
{
    __shared__ float px[NPTS], py[NPTS], pz[NPTS];
    __shared__ unsigned long long keys[256];
    __shared__ unsigned long long winner;
    const int b = blockIdx.x, tid = threadIdx.x;
    const float* base = xyz + b * 3 * NPTS;
    for (int i = tid; i < NPTS; i += 256) {
        px[i] = base[i]; py[i] = base[NPTS + i]; pz[i] = base[2 * NPTS + i];
    }
    __syncthreads();

    float X[16], Y[16], Z[16], D[16];
#pragma unroll
    for (int j = 0; j < 16; ++j) {
        int n = j * 256 + tid;
        X[j] = px[n]; Y[j] = py[n]; Z[j] = pz[n]; D[j] = 1e10f;
    }
    int farthest = 0;
    float* ox = outx + b * 3 * NPOINT;

    for (int t = 0; t < NPOINT; ++t) {
        if (tid == 0) {
            fidx[b * NPOINT + t] = farthest;
            ox[t]              = px[farthest];
            ox[NPOINT + t]     = py[farthest];
            ox[2 * NPOINT + t] = pz[farthest];
        }
        const float cx = px[farthest], cy = py[farthest], cz = pz[farthest];
        float bv = -1.0f; int bi = 0;
#pragma unroll
        for (int j = 0; j < 16; ++j) {
            float dx = __fsub_rn(X[j], cx);
            float dy = __fsub_rn(Y[j], cy);
            float dz = __fsub_rn(Z[j], cz);
            float d = __fadd_rn(__fadd_rn(__fmul_rn(dx, dx), __fmul_rn(dy, dy)),
                                __fmul_rn(dz, dz));
            float nd = fminf(D[j], d);
            D[j] = nd;
            if (nd > bv) { bv = nd; bi = j * 256 + tid; }   // ascending idx within thread
        }
        // pack (value, ~idx): u64 max == lexicographic max on (v, smaller idx wins)
        keys[tid] = ((unsigned long long)__float_as_uint(bv) << 32) |
                    (unsigned int)(~bi);
        __syncthreads();
        if (tid < 64) {
            unsigned long long k = keys[tid];
            unsigned long long o;
            o = keys[tid + 64];  if (o > k) k = o;
            o = keys[tid + 128]; if (o > k) k = o;
            o = keys[tid + 192]; if (o > k) k = o;
#pragma unroll
            for (int off = 32; off; off >>= 1) {
                unsigned int hi = __shfl_down((unsigned int)(k >> 32), off);
                unsigned int lo = __shfl_down((unsigned int)(k & 0xffffffffu), off);
                unsigned long long ok = ((unsigned long long)hi << 32) | lo;
                if (ok > k) k = ok;
            }
            if (tid == 0) winner = k;
        }
        __syncthreads();
        farthest = (int)(~(unsigned int)(winner & 0xffffffffull)) & (NPTS - 1);
    }
}

// ---------------------------------------------------------------------------
// Ball query: one wave per query; first 32 in-radius indices in ascending order
// ---------------------------------------------------------------------------
__global__ __launch_bounds__(256) void ball_kernel(const float* __restrict__ xyz,
                                                   const float* __restrict__ outx,
                                                   int* __restrict__ idxbuf)
{
    const int w = blockIdx.x * 4 + (threadIdx.x >> 6);
    const int lane = threadIdx.x & 63;
    const int b = w >> 10, s = w & 1023;
    const float* base = xyz + b * 3 * NPTS;
    const float cx = outx[b * 3 * NPOINT + s];
    const float cy = outx[b * 3 * NPOINT + NPOINT + s];
    const float cz = outx[b * 3 * NPOINT + 2 * NPOINT + s];
    const float sumS = __fadd_rn(__fadd_rn(__fmul_rn(cx, cx), __fmul_rn(cy, cy)),
                                 __fmul_rn(cz, cz));
    int cnt = 0, first_n = -1;
    int* myidx = idxbuf + w * NSAMP;

    for (int chunk = 0; chunk < NPTS / 64 && cnt < NSAMP; ++chunk) {
        const int n = chunk * 64 + lane;
        float nx = base[n], ny = base[NPTS + n], nz = base[2 * NPTS + n];
        float sumN = __fadd_rn(__fadd_rn(__fmul_rn(nx, nx), __fmul_rn(ny, ny)),
                               __fmul_rn(nz, nz));
        float dot = __fadd_rn(__fadd_rn(__fmul_rn(cx, nx), __fmul_rn(cy, ny)),
                              __fmul_rn(cz, nz));
        float sq = __fsub_rn(__fadd_rn(sumS, sumN), __fmul_rn(2.0f, dot));
        bool keep = (sq <= RAD2);
        unsigned long long mask = __ballot(keep);
        if (first_n < 0 && mask) first_n = chunk * 64 + (int)__builtin_ctzll(mask);
        int pos = cnt + __popcll(mask & ((1ull << lane) - 1ull));
        if (keep && pos < NSAMP) myidx[pos] = n;
        cnt += __popcll(mask);
    }
    if (cnt < NSAMP) {
        if (lane >= cnt && lane < NSAMP) myidx[lane] = first_n;
    }
}

// ---------------------------------------------------------------------------
// helpers
// ---------------------------------------------------------------------------
__device__ __forceinline__ void load_feats(const float* __restrict__ xyz,
                                           const float* __restrict__ pts,
                                           const float* __restrict__ outx,
                                           int r, int idx, float f[6])
{
    const int b = r >> 15;
    const int s = (r >> 5) & 1023;
    const float* xb = xyz + b * 3 * NPTS;
    const float* pb = pts + b * 3 * NPTS;
    const float* ob = outx + b * 3 * NPOINT;
    f[0] = xb[idx] - ob[s];
    f[1] = xb[NPTS + idx] - ob[NPOINT + s];
    f[2] = xb[2 * NPTS + idx] - ob[2 * NPOINT + s];
    f[3] = pb[idx];
    f[4] = pb[NPTS + idx];
    f[5] = pb[2 * NPTS + idx];
}

__device__ __forceinline__ void compute_x1(const float f[6],
                                           const float* __restrict__ w0,
                                           const float* __restrict__ b0,
                                           const float* __restrict__ bn0,
                                           float x1[64])
{
#pragma unroll
    for (int o = 0; o < 64; ++o) {
        float a = b0[o];
#pragma unroll
        for (int c = 0; c < 6; ++c) a = fmaf(f[c], w0[o * 6 + c], a);
        a = fmaf(a, bn0[o], bn0[64 + o]);
        x1[o] = fmaxf(a, 0.0f);
    }
}

// ---------------------------------------------------------------------------
// P0: per-channel sums of y0 (lane = channel, rows looped, uniform loads)
// ---------------------------------------------------------------------------
__global__ __launch_bounds__(64) void stats0_kernel(const float* __restrict__ xyz,
                                                    const float* __restrict__ pts,
                                                    const float* __restrict__ outx,
                                                    const int* __restrict__ idxbuf,
                                                    const float* __restrict__ w0,
                                                    const float* __restrict__ b0,
                                                    float* __restrict__ stats)
{
    const int lane = threadIdx.x;
    float w[6];
#pragma unroll
    for (int c = 0; c < 6; ++c) w[c] = w0[lane * 6 + c];
    const float bb = b0[lane];
    float s = 0.f, q = 0.f;
    const int r0 = blockIdx.x * 128;
    for (int r = r0; r < r0 + 128; ++r) {
        int idx = idxbuf[r];
        float f[6];
        load_feats(xyz, pts, outx, r, idx, f);
        float y = bb;
#pragma unroll
        for (int c = 0; c < 6; ++c) y = fmaf(f[c], w[c], y);
        s += y;
        q = fmaf(y, y, q);
    }
    atomicAdd(&stats[lane], s);
    atomicAdd(&stats[64 + lane], q);
}

// ---------------------------------------------------------------------------
// BN param kernel: scale = g*rsqrt(var+eps); shift = be - mean*scale
// ---------------------------------------------------------------------------
__global__ void bnparam_kernel(const float* __restrict__ stats,
                               const float* __restrict__ g,
                               const float* __restrict__ be,
                               float* __restrict__ bn, int C)
{
    const int t = threadIdx.x;
    if (t >= C) return;
    const float inv = 1.0f / (float)NROWS;
    float mean = stats[t] * inv;
    float var = stats[C + t] * inv - mean * mean;
    float scale = g[t] * rsqrtf(var + 1e-5f);
    bn[t] = scale;
    bn[C + t] = be[t] - mean * scale;
}

// ---------------------------------------------------------------------------
// P1: recompute x1, y1 = W1 x1 + b1; per-channel sum/sumsq via LDS col-reduce
// ---------------------------------------------------------------------------
__global__ __launch_bounds__(64) void stats1_kernel(const float* __restrict__ xyz,
                                                    const float* __restrict__ pts,
                                                    const float* __restrict__ outx,
                                                    const int* __restrict__ idxbuf,
                                                    const float* __restrict__ w0,
                                                    const float* __restrict__ b0,
                                                    const float* __restrict__ bn0,
                                                    const float* __restrict__ w1,
                                                    const float* __restrict__ b1,
                                                    float* __restrict__ stats)
{
    __shared__ float tile[64 * 65];
    const int lane = threadIdx.x;
    const int r = blockIdx.x * 64 + lane;
    int idx = idxbuf[r];
    float f[6];
    load_feats(xyz, pts, outx, r, idx, f);
    float x1[64];
    compute_x1(f, w0, b0, bn0, x1);

    for (int o = 0; o < 64; ++o) {
        float a = b1[o];
#pragma unroll
        for (int c = 0; c < 64; ++c) a = fmaf(x1[c], w1[o * 64 + c], a);
        tile[o * 65 + lane] = a;
    }
    __syncthreads();
    float s = 0.f, q = 0.f;
    for (int rr = 0; rr < 64; ++rr) {
        float v = tile[lane * 65 + rr];
        s += v;
        q = fmaf(v, v, q);
    }
    atomicAdd(&stats[lane], s);
    atomicAdd(&stats[64 + lane], q);
}

// ---------------------------------------------------------------------------
// P2: recompute through y2 = W2 x2 + b2; per-channel sums AND per-group k-max
// (g>0 so relu∘bn2 is monotone: max can be taken pre-bn2)
// ---------------------------------------------------------------------------
__global__ __launch_bounds__(64) void stats2_kernel(const float* __restrict__ xyz,
                                                    const float* __restrict__ pts,
                                                    const float* __restrict__ outx,
                                                    const int* __restrict__ idxbuf,
                                                    const float* __restrict__ w0,
                                                    const float* __restrict__ b0,
                                                    const float* __restrict__ bn0,
                                                    const float* __restrict__ w1,
                                                    const float* __restrict__ b1,
                                                    const float* __restrict__ bn1,
                                                    const float* __restrict__ w2,
                                                    const float* __restrict__ b2,
                                                    float* __restrict__ stats,
                                                    float* __restrict__ gmax)
{
    __shared__ float tile[64 * 65];
    const int lane = threadIdx.x;
    const int r = blockIdx.x * 64 + lane;
    int idx = idxbuf[r];
    float f[6];
    load_feats(xyz, pts, outx, r, idx, f);
    float x1[64];
    compute_x1(f, w0, b0, bn0, x1);

    for (int o = 0; o < 64; ++o) {
        float a = b1[o];
#pragma unroll
        for (int c = 0; c < 64; ++c) a = fmaf(x1[c], w1[o * 64 + c], a);
        tile[o * 65 + lane] = a;
    }
    __syncthreads();
    float x2[64];
#pragma unroll
    for (int c = 0; c < 64; ++c) {
        float v = tile[c * 65 + lane];
        v = fmaf(v, bn1[c], bn1[64 + c]);
        x2[c] = fmaxf(v, 0.0f);
    }
    const int g0 = blockIdx.x * 2;
    for (int h = 0; h < 2; ++h) {
        __syncthreads();
        for (int oi = 0; oi < 64; ++oi) {
            const int o2 = h * 64 + oi;
            float a = b2[o2];
#pragma unroll
            for (int c = 0; c < 64; ++c) a = fmaf(x2[c], w2[o2 * 64 + c], a);
            tile[oi * 65 + lane] = a;
        }
        __syncthreads();
        float s = 0.f, q = 0.f, mA = -1e30f, mB = -1e30f;
        for (int rr = 0; rr < 32; ++rr) {
            float v = tile[lane * 65 + rr];
            s += v; q = fmaf(v, v, q); mA = fmaxf(mA, v);
        }
        for (int rr = 32; rr < 64; ++rr) {
            float v = tile[lane * 65 + rr];
            s += v; q = fmaf(v, v, q); mB = fmaxf(mB, v);
        }
        const int o2 = h * 64 + lane;
        atomicAdd(&stats[o2], s);
        atomicAdd(&stats[128 + o2], q);
        gmax[o2 * 8192 + g0]     = mA;
        gmax[o2 * 8192 + g0 + 1] = mB;
    }
}

// ---------------------------------------------------------------------------
// P3: out2[b,o,s] = relu(bn2(gmax[o, b*1024+s]))
// ---------------------------------------------------------------------------
__global__ __launch_bounds__(256) void final_kernel(const float* __restrict__ gmax,
                                                    const float* __restrict__ bn2,
                                                    float* __restrict__ out2)
{
    const int t = blockIdx.x * 256 + threadIdx.x;
    const int s = t & 1023;
    const int o = (t >> 10) & 127;
    const int b = t >> 17;
    const int g = (b << 10) | s;
    float v = gmax[o * 8192 + g];
    v = fmaf(v, bn2[o], bn2[128 + o]);
    out2[t] = fmaxf(v, 0.0f);
}

// ---------------------------------------------------------------------------
extern "C" void kernel_launch(void* const* d_in, const int* in_sizes, int n_in,
                              void* d_out, int out_size, void* d_ws, size_t ws_size,
                              hipStream_t stream)
{
    const float* xyz = (const float*)d_in[0];
    const float* pts = (const float*)d_in[1];
    const float* w0  = (const float*)d_in[2];
    const float* b0  = (const float*)d_in[3];
    const float* g0  = (const float*)d_in[4];
    const float* be0 = (const float*)d_in[5];
    const float* w1  = (const float*)d_in[6];
    const float* b1  = (const float*)d_in[7];
    const float* g1  = (const float*)d_in[8];
    const float* be1 = (const float*)d_in[9];
    const float* w2  = (const float*)d_in[10];
    const float* b2  = (const float*)d_in[11];
    const float* g2  = (const float*)d_in[12];
    const float* be2 = (const float*)d_in[13];

    float* out_xyz = (float*)d_out;             // (B,3,1024) = 24576 floats
    float* out2    = out_xyz + 8 * 3 * NPOINT;  // (B,128,1024)

    char* wsb = (char*)d_ws;
    int*   fidx   = (int*)wsb;                         // 8192 ints
    int*   idxbuf = (int*)(wsb + 32768);               // 262144 ints
    float* stats  = (float*)(wsb + 32768 + 1048576);   // 512 floats
    float* bnp    = stats + 512;                       // 512 floats
    float* gmax   = bnp + 512;                         // 128*8192 floats

    float* stats0 = stats;       float* stats1 = stats + 128; float* stats2 = stats + 256;
    float* bn0    = bnp;         float* bn1    = bnp + 128;   float* bn2    = bnp + 256;

    hipMemsetAsync(stats, 0, 512 * sizeof(float), stream);

    fps_kernel<<<8, 256, 0, stream>>>(xyz, out_xyz, fidx);
    ball_kernel<<<2048, 256, 0, stream>>>(xyz, out_xyz, idxbuf);
    stats0_kernel<<<2048, 64, 0, stream>>>(xyz, pts, out_xyz, idxbuf, w0, b0, stats0);
    bnparam_kernel<<<1, 64, 0, stream>>>(stats0, g0, be0, bn0, 64);
    stats1_kernel<<<4096, 64, 0, stream>>>(xyz, pts, out_xyz, idxbuf, w0, b0, bn0, w1, b1, stats1);
    bnparam_kernel<<<1, 64, 0, stream>>>(stats1, g1, be1, bn1, 64);
    stats2_kernel<<<4096, 64, 0, stream>>>(xyz, pts, out_xyz, idxbuf, w0, b0, bn0, w1, b1, bn1, w2, b2, stats2, gmax);
    bnparam_kernel<<<1, 128, 0, stream>>>(stats2, g2, be2, bn2, 128);
    final_kernel<<<4096, 256, 0, stream>>>(gmax, bn2, out2);
}

// Round 2
// 1413.015 us; speedup vs baseline: 1.0804x; 1.0804x over previous
//
#include <hip/hip_runtime.h>
#include <stdint.h>

#define NPTS   4096
#define NPOINT 1024
#define NSAMP  32
#define NROWS  262144   // B*NPOINT*NSAMP
#define RAD2   0.04f

// ---------------------------------------------------------------------------
// FPS: one block per batch, bit-exact distance chain vs fp32 reference.
// Reduction: per-wave 64-bit butterfly (parallel) -> 4 keys in LDS -> ONE
// barrier -> every thread reduces 4 keys locally. Key slots double-buffered
// on iteration parity so no second barrier is needed.
// ---------------------------------------------------------------------------
__global__ __launch_bounds__(256) void fps_kernel(const float* __restrict__ xyz,
                                                  float* __restrict__ outx,
                                                  int* __restrict__ fidx)
{
    __shared__ float px[NPTS], py[NPTS], pz[NPTS];
    __shared__ __align__(16) unsigned long long wavekeys[2][4];
    const int b = blockIdx.x, tid = threadIdx.x;
    const int lane = tid & 63, wid = tid >> 6;
    const float* base = xyz + b * 3 * NPTS;

    float X[16], Y[16], Z[16], D[16];
#pragma unroll
    for (int j = 0; j < 16; ++j) {
        const int n = j * 256 + tid;
        X[j] = base[n];
        Y[j] = base[NPTS + n];
        Z[j] = base[2 * NPTS + n];
        D[j] = 1e10f;
        px[n] = X[j]; py[n] = Y[j]; pz[n] = Z[j];
    }
    __syncthreads();

    int farthest = 0;
    float* ox = outx + b * 3 * NPOINT;

    for (int t = 0; t < NPOINT; ++t) {
        const float cx = px[farthest], cy = py[farthest], cz = pz[farthest];
        if (tid == 0) {
            fidx[b * NPOINT + t] = farthest;
            ox[t]              = cx;
            ox[NPOINT + t]     = cy;
            ox[2 * NPOINT + t] = cz;
        }
        float bv = -1.0f; int bi = 0;
#pragma unroll
        for (int j = 0; j < 16; ++j) {
            float dx = __fsub_rn(X[j], cx);
            float dy = __fsub_rn(Y[j], cy);
            float dz = __fsub_rn(Z[j], cz);
            float d = __fadd_rn(__fadd_rn(__fmul_rn(dx, dx), __fmul_rn(dy, dy)),
                                __fmul_rn(dz, dz));
            float nd = fminf(D[j], d);
            D[j] = nd;
            if (nd > bv) { bv = nd; bi = j * 256 + tid; }   // earliest idx per thread
        }
        // pack (value, ~idx): u64 max == lexicographic (max value, min idx)
        unsigned long long k = ((unsigned long long)__float_as_uint(bv) << 32) |
                               (unsigned int)(~bi);
        // in-wave butterfly reduce (all 4 waves concurrently, no barrier)
#pragma unroll
        for (int off = 32; off; off >>= 1) {
            unsigned long long ok = __shfl_down(k, off);
            if (ok > k) k = ok;
        }
        if (lane == 0) wavekeys[t & 1][wid] = k;
        __syncthreads();
        const ulonglong2* wk = (const ulonglong2*)wavekeys[t & 1];
        ulonglong2 ka = wk[0], kb = wk[1];
        unsigned long long kk = ka.x;
        if (ka.y > kk) kk = ka.y;
        if (kb.x > kk) kk = kb.x;
        if (kb.y > kk) kk = kb.y;
        farthest = (int)(~(unsigned int)(kk & 0xffffffffull)) & (NPTS - 1);
    }
}

// ---------------------------------------------------------------------------
// Ball query: one wave per query; first 32 in-radius indices in ascending order
// ---------------------------------------------------------------------------
__global__ __launch_bounds__(256) void ball_kernel(const float* __restrict__ xyz,
                                                   const float* __restrict__ outx,
                                                   int* __restrict__ idxbuf)
{
    const int w = blockIdx.x * 4 + (threadIdx.x >> 6);
    const int lane = threadIdx.x & 63;
    const int b = w >> 10, s = w & 1023;
    const float* base = xyz + b * 3 * NPTS;
    const float cx = outx[b * 3 * NPOINT + s];
    const float cy = outx[b * 3 * NPOINT + NPOINT + s];
    const float cz = outx[b * 3 * NPOINT + 2 * NPOINT + s];
    const float sumS = __fadd_rn(__fadd_rn(__fmul_rn(cx, cx), __fmul_rn(cy, cy)),
                                 __fmul_rn(cz, cz));
    int cnt = 0, first_n = -1;
    int* myidx = idxbuf + w * NSAMP;

    for (int chunk = 0; chunk < NPTS / 64 && cnt < NSAMP; ++chunk) {
        const int n = chunk * 64 + lane;
        float nx = base[n], ny = base[NPTS + n], nz = base[2 * NPTS + n];
        float sumN = __fadd_rn(__fadd_rn(__fmul_rn(nx, nx), __fmul_rn(ny, ny)),
                               __fmul_rn(nz, nz));
        float dot = __fadd_rn(__fadd_rn(__fmul_rn(cx, nx), __fmul_rn(cy, ny)),
                              __fmul_rn(cz, nz));
        float sq = __fsub_rn(__fadd_rn(sumS, sumN), __fmul_rn(2.0f, dot));
        bool keep = (sq <= RAD2);
        unsigned long long mask = __ballot(keep);
        if (first_n < 0 && mask) first_n = chunk * 64 + (int)__builtin_ctzll(mask);
        int pos = cnt + __popcll(mask & ((1ull << lane) - 1ull));
        if (keep && pos < NSAMP) myidx[pos] = n;
        cnt += __popcll(mask);
    }
    if (cnt < NSAMP) {
        if (lane >= cnt && lane < NSAMP) myidx[lane] = first_n;
    }
}

// ---------------------------------------------------------------------------
// helpers
// ---------------------------------------------------------------------------
__device__ __forceinline__ void load_feats(const float* __restrict__ xyz,
                                           const float* __restrict__ pts,
                                           const float* __restrict__ outx,
                                           int r, int idx, float f[6])
{
    const int b = r >> 15;
    const int s = (r >> 5) & 1023;
    const float* xb = xyz + b * 3 * NPTS;
    const float* pb = pts + b * 3 * NPTS;
    const float* ob = outx + b * 3 * NPOINT;
    f[0] = xb[idx] - ob[s];
    f[1] = xb[NPTS + idx] - ob[NPOINT + s];
    f[2] = xb[2 * NPTS + idx] - ob[2 * NPOINT + s];
    f[3] = pb[idx];
    f[4] = pb[NPTS + idx];
    f[5] = pb[2 * NPTS + idx];
}

__device__ __forceinline__ void compute_x1(const float f[6],
                                           const float* __restrict__ w0,
                                           const float* __restrict__ b0,
                                           const float* __restrict__ bn0,
                                           float x1[64])
{
#pragma unroll
    for (int o = 0; o < 64; ++o) {
        float a = b0[o];
#pragma unroll
        for (int c = 0; c < 6; ++c) a = fmaf(f[c], w0[o * 6 + c], a);
        a = fmaf(a, bn0[o], bn0[64 + o]);
        x1[o] = fmaxf(a, 0.0f);
    }
}

// ---------------------------------------------------------------------------
// P0: per-channel sums of y0 (lane = channel, rows looped, uniform loads)
// ---------------------------------------------------------------------------
__global__ __launch_bounds__(64) void stats0_kernel(const float* __restrict__ xyz,
                                                    const float* __restrict__ pts,
                                                    const float* __restrict__ outx,
                                                    const int* __restrict__ idxbuf,
                                                    const float* __restrict__ w0,
                                                    const float* __restrict__ b0,
                                                    float* __restrict__ stats)
{
    const int lane = threadIdx.x;
    float w[6];
#pragma unroll
    for (int c = 0; c < 6; ++c) w[c] = w0[lane * 6 + c];
    const float bb = b0[lane];
    float s = 0.f, q = 0.f;
    const int r0 = blockIdx.x * 128;
    for (int r = r0; r < r0 + 128; ++r) {
        int idx = idxbuf[r];
        float f[6];
        load_feats(xyz, pts, outx, r, idx, f);
        float y = bb;
#pragma unroll
        for (int c = 0; c < 6; ++c) y = fmaf(f[c], w[c], y);
        s += y;
        q = fmaf(y, y, q);
    }
    atomicAdd(&stats[lane], s);
    atomicAdd(&stats[64 + lane], q);
}

// ---------------------------------------------------------------------------
// BN param kernel: scale = g*rsqrt(var+eps); shift = be - mean*scale
// ---------------------------------------------------------------------------
__global__ void bnparam_kernel(const float* __restrict__ stats,
                               const float* __restrict__ g,
                               const float* __restrict__ be,
                               float* __restrict__ bn, int C)
{
    const int t = threadIdx.x;
    if (t >= C) return;
    const float inv = 1.0f / (float)NROWS;
    float mean = stats[t] * inv;
    float var = stats[C + t] * inv - mean * mean;
    float scale = g[t] * rsqrtf(var + 1e-5f);
    bn[t] = scale;
    bn[C + t] = be[t] - mean * scale;
}

// ---------------------------------------------------------------------------
// P1: recompute x1, y1 = W1 x1 + b1; per-channel sum/sumsq via LDS col-reduce
// ---------------------------------------------------------------------------
__global__ __launch_bounds__(64) void stats1_kernel(const float* __restrict__ xyz,
                                                    const float* __restrict__ pts,
                                                    const float* __restrict__ outx,
                                                    const int* __restrict__ idxbuf,
                                                    const float* __restrict__ w0,
                                                    const float* __restrict__ b0,
                                                    const float* __restrict__ bn0,
                                                    const float* __restrict__ w1,
                                                    const float* __restrict__ b1,
                                                    float* __restrict__ stats)
{
    __shared__ float tile[64 * 65];
    const int lane = threadIdx.x;
    const int r = blockIdx.x * 64 + lane;
    int idx = idxbuf[r];
    float f[6];
    load_feats(xyz, pts, outx, r, idx, f);
    float x1[64];
    compute_x1(f, w0, b0, bn0, x1);

    for (int o = 0; o < 64; ++o) {
        float a = b1[o];
#pragma unroll
        for (int c = 0; c < 64; ++c) a = fmaf(x1[c], w1[o * 64 + c], a);
        tile[o * 65 + lane] = a;
    }
    __syncthreads();
    float s = 0.f, q = 0.f;
    for (int rr = 0; rr < 64; ++rr) {
        float v = tile[lane * 65 + rr];
        s += v;
        q = fmaf(v, v, q);
    }
    atomicAdd(&stats[lane], s);
    atomicAdd(&stats[64 + lane], q);
}

// ---------------------------------------------------------------------------
// P2: recompute through y2 = W2 x2 + b2; per-channel sums AND per-group k-max
// (g>0 so relu∘bn2 is monotone: max can be taken pre-bn2)
// ---------------------------------------------------------------------------
__global__ __launch_bounds__(64) void stats2_kernel(const float* __restrict__ xyz,
                                                    const float* __restrict__ pts,
                                                    const float* __restrict__ outx,
                                                    const int* __restrict__ idxbuf,
                                                    const float* __restrict__ w0,
                                                    const float* __restrict__ b0,
                                                    const float* __restrict__ bn0,
                                                    const float* __restrict__ w1,
                                                    const float* __restrict__ b1,
                                                    const float* __restrict__ bn1,
                                                    const float* __restrict__ w2,
                                                    const float* __restrict__ b2,
                                                    float* __restrict__ stats,
                                                    float* __restrict__ gmax)
{
    __shared__ float tile[64 * 65];
    const int lane = threadIdx.x;
    const int r = blockIdx.x * 64 + lane;
    int idx = idxbuf[r];
    float f[6];
    load_feats(xyz, pts, outx, r, idx, f);
    float x1[64];
    compute_x1(f, w0, b0, bn0, x1);

    for (int o = 0; o < 64; ++o) {
        float a = b1[o];
#pragma unroll
        for (int c = 0; c < 64; ++c) a = fmaf(x1[c], w1[o * 64 + c], a);
        tile[o * 65 + lane] = a;
    }
    __syncthreads();
    float x2[64];
#pragma unroll
    for (int c = 0; c < 64; ++c) {
        float v = tile[c * 65 + lane];
        v = fmaf(v, bn1[c], bn1[64 + c]);
        x2[c] = fmaxf(v, 0.0f);
    }
    const int g0 = blockIdx.x * 2;
    for (int h = 0; h < 2; ++h) {
        __syncthreads();
        for (int oi = 0; oi < 64; ++oi) {
            const int o2 = h * 64 + oi;
            float a = b2[o2];
#pragma unroll
            for (int c = 0; c < 64; ++c) a = fmaf(x2[c], w2[o2 * 64 + c], a);
            tile[oi * 65 + lane] = a;
        }
        __syncthreads();
        float s = 0.f, q = 0.f, mA = -1e30f, mB = -1e30f;
        for (int rr = 0; rr < 32; ++rr) {
            float v = tile[lane * 65 + rr];
            s += v; q = fmaf(v, v, q); mA = fmaxf(mA, v);
        }
        for (int rr = 32; rr < 64; ++rr) {
            float v = tile[lane * 65 + rr];
            s += v; q = fmaf(v, v, q); mB = fmaxf(mB, v);
        }
        const int o2 = h * 64 + lane;
        atomicAdd(&stats[o2], s);
        atomicAdd(&stats[128 + o2], q);
        gmax[o2 * 8192 + g0]     = mA;
        gmax[o2 * 8192 + g0 + 1] = mB;
    }
}

// ---------------------------------------------------------------------------
// P3: out2[b,o,s] = relu(bn2(gmax[o, b*1024+s]))
// ---------------------------------------------------------------------------
__global__ __launch_bounds__(256) void final_kernel(const float* __restrict__ gmax,
                                                    const float* __restrict__ bn2,
                                                    float* __restrict__ out2)
{
    const int t = blockIdx.x * 256 + threadIdx.x;
    const int s = t & 1023;
    const int o = (t >> 10) & 127;
    const int b = t >> 17;
    const int g = (b << 10) | s;
    float v = gmax[o * 8192 + g];
    v = fmaf(v, bn2[o], bn2[128 + o]);
    out2[t] = fmaxf(v, 0.0f);
}

// ---------------------------------------------------------------------------
extern "C" void kernel_launch(void* const* d_in, const int* in_sizes, int n_in,
                              void* d_out, int out_size, void* d_ws, size_t ws_size,
                              hipStream_t stream)
{
    const float* xyz = (const float*)d_in[0];
    const float* pts = (const float*)d_in[1];
    const float* w0  = (const float*)d_in[2];
    const float* b0  = (const float*)d_in[3];
    const float* g0  = (const float*)d_in[4];
    const float* be0 = (const float*)d_in[5];
    const float* w1  = (const float*)d_in[6];
    const float* b1  = (const float*)d_in[7];
    const float* g1  = (const float*)d_in[8];
    const float* be1 = (const float*)d_in[9];
    const float* w2  = (const float*)d_in[10];
    const float* b2  = (const float*)d_in[11];
    const float* g2  = (const float*)d_in[12];
    const float* be2 = (const float*)d_in[13];

    float* out_xyz = (float*)d_out;             // (B,3,1024) = 24576 floats
    float* out2    = out_xyz + 8 * 3 * NPOINT;  // (B,128,1024)

    char* wsb = (char*)d_ws;
    int*   fidx   = (int*)wsb;                         // 8192 ints
    int*   idxbuf = (int*)(wsb + 32768);               // 262144 ints
    float* stats  = (float*)(wsb + 32768 + 1048576);   // 512 floats
    float* bnp    = stats + 512;                       // 512 floats
    float* gmax   = bnp + 512;                         // 128*8192 floats

    float* stats0 = stats;       float* stats1 = stats + 128; float* stats2 = stats + 256;
    float* bn0    = bnp;         float* bn1    = bnp + 128;   float* bn2    = bnp + 256;

    hipMemsetAsync(stats, 0, 512 * sizeof(float), stream);

    fps_kernel<<<8, 256, 0, stream>>>(xyz, out_xyz, fidx);
    ball_kernel<<<2048, 256, 0, stream>>>(xyz, out_xyz, idxbuf);
    stats0_kernel<<<2048, 64, 0, stream>>>(xyz, pts, out_xyz, idxbuf, w0, b0, stats0);
    bnparam_kernel<<<1, 64, 0, stream>>>(stats0, g0, be0, bn0, 64);
    stats1_kernel<<<4096, 64, 0, stream>>>(xyz, pts, out_xyz, idxbuf, w0, b0, bn0, w1, b1, stats1);
    bnparam_kernel<<<1, 64, 0, stream>>>(stats1, g1, be1, bn1, 64);
    stats2_kernel<<<4096, 64, 0, stream>>>(xyz, pts, out_xyz, idxbuf, w0, b0, bn0, w1, b1, bn1, w2, b2, stats2, gmax);
    bnparam_kernel<<<1, 128, 0, stream>>>(stats2, g2, be2, bn2, 128);
    final_kernel<<<4096, 256, 0, stream>>>(gmax, bn2, out2);
}

// Round 3
// 1375.680 us; speedup vs baseline: 1.1098x; 1.0271x over previous
//
#include <hip/hip_runtime.h>
#include <stdint.h>

#define NPTS   4096
#define NPOINT 1024
#define NSAMP  32
#define NROWS  262144   // B*NPOINT*NSAMP
#define RAD2   0.04f

// ---------------------------------------------------------------------------
// FPS: one block per batch. Bit-exact distance chain vs fp32 reference.
// Per iter: compute+argmax -> u64 xor-butterfly (per wave, parallel) ->
// lane0 writes wave key -> ONE barrier -> all threads reduce 4 keys ->
// single ds_read_b128 for winner coords. Key slots parity double-buffered.
// ---------------------------------------------------------------------------
__global__ __launch_bounds__(256) void fps_kernel(const float* __restrict__ xyz,
                                                  float* __restrict__ outx)
{
    __shared__ __align__(16) float4 pxyz[NPTS];
    __shared__ __align__(16) unsigned long long wkey[2][4];
    const int b = blockIdx.x, tid = threadIdx.x;
    const int lane = tid & 63, wid = tid >> 6;
    const float* base = xyz + b * 3 * NPTS;

    float X[16], Y[16], Z[16], D[16];
#pragma unroll
    for (int j = 0; j < 16; ++j) {
        const int n = j * 256 + tid;
        X[j] = base[n];
        Y[j] = base[NPTS + n];
        Z[j] = base[2 * NPTS + n];
        D[j] = 1e10f;
        pxyz[n] = make_float4(X[j], Y[j], Z[j], 0.0f);
    }
    __syncthreads();
    float4 c4 = pxyz[0];
    float cx = c4.x, cy = c4.y, cz = c4.z;
    float* ox = outx + b * 3 * NPOINT;

    for (int t = 0; t < NPOINT; ++t) {
        if (tid == 0) {
            ox[t]              = cx;
            ox[NPOINT + t]     = cy;
            ox[2 * NPOINT + t] = cz;
        }
        float bv = -1.0f; int bi = 0;
#pragma unroll
        for (int j = 0; j < 16; ++j) {
            float dx = __fsub_rn(X[j], cx);
            float dy = __fsub_rn(Y[j], cy);
            float dz = __fsub_rn(Z[j], cz);
            float d = __fadd_rn(__fadd_rn(__fmul_rn(dx, dx), __fmul_rn(dy, dy)),
                                __fmul_rn(dz, dz));
            float nd = fminf(D[j], d);
            D[j] = nd;
            if (nd > bv) { bv = nd; bi = j * 256 + tid; }   // earliest idx per thread
        }
        // pack (value, ~idx): u64 max == lexicographic (max value, min idx)
        unsigned long long k = ((unsigned long long)__float_as_uint(bv) << 32) |
                               (unsigned int)(~bi);
#pragma unroll
        for (int off = 1; off < 64; off <<= 1) {
            unsigned long long ok = __shfl_xor(k, off);
            if (ok > k) k = ok;
        }
        if (lane == 0) wkey[t & 1][wid] = k;
        __syncthreads();
        const ulonglong2* wk = (const ulonglong2*)wkey[t & 1];
        ulonglong2 ka = wk[0], kb = wk[1];
        unsigned long long kk = ka.x;
        if (ka.y > kk) kk = ka.y;
        if (kb.x > kk) kk = kb.x;
        if (kb.y > kk) kk = kb.y;
        const int farthest = (int)(~(unsigned int)kk) & (NPTS - 1);
        c4 = pxyz[farthest];
        cx = c4.x; cy = c4.y; cz = c4.z;
    }
}

// ---------------------------------------------------------------------------
// Ball query: one wave per query; first 32 in-radius indices in ascending order
// ---------------------------------------------------------------------------
__global__ __launch_bounds__(256) void ball_kernel(const float* __restrict__ xyz,
                                                   const float* __restrict__ outx,
                                                   int* __restrict__ idxbuf)
{
    const int w = blockIdx.x * 4 + (threadIdx.x >> 6);
    const int lane = threadIdx.x & 63;
    const int b = w >> 10, s = w & 1023;
    const float* base = xyz + b * 3 * NPTS;
    const float cx = outx[b * 3 * NPOINT + s];
    const float cy = outx[b * 3 * NPOINT + NPOINT + s];
    const float cz = outx[b * 3 * NPOINT + 2 * NPOINT + s];
    const float sumS = __fadd_rn(__fadd_rn(__fmul_rn(cx, cx), __fmul_rn(cy, cy)),
                                 __fmul_rn(cz, cz));
    int cnt = 0, first_n = -1;
    int* myidx = idxbuf + w * NSAMP;

    for (int chunk = 0; chunk < NPTS / 64 && cnt < NSAMP; ++chunk) {
        const int n = chunk * 64 + lane;
        float nx = base[n], ny = base[NPTS + n], nz = base[2 * NPTS + n];
        float sumN = __fadd_rn(__fadd_rn(__fmul_rn(nx, nx), __fmul_rn(ny, ny)),
                               __fmul_rn(nz, nz));
        float dot = __fadd_rn(__fadd_rn(__fmul_rn(cx, nx), __fmul_rn(cy, ny)),
                              __fmul_rn(cz, nz));
        float sq = __fsub_rn(__fadd_rn(sumS, sumN), __fmul_rn(2.0f, dot));
        bool keep = (sq <= RAD2);
        unsigned long long mask = __ballot(keep);
        if (first_n < 0 && mask) first_n = chunk * 64 + (int)__builtin_ctzll(mask);
        int pos = cnt + __popcll(mask & ((1ull << lane) - 1ull));
        if (keep && pos < NSAMP) myidx[pos] = n;
        cnt += __popcll(mask);
    }
    if (cnt < NSAMP) {
        if (lane >= cnt && lane < NSAMP) myidx[lane] = first_n;
    }
}

// ---------------------------------------------------------------------------
// helpers
// ---------------------------------------------------------------------------
__device__ __forceinline__ void load_feats(const float* __restrict__ xyz,
                                           const float* __restrict__ pts,
                                           const float* __restrict__ outx,
                                           int r, int idx, float f[6])
{
    const int b = r >> 15;
    const int s = (r >> 5) & 1023;
    const float* xb = xyz + b * 3 * NPTS;
    const float* pb = pts + b * 3 * NPTS;
    const float* ob = outx + b * 3 * NPOINT;
    f[0] = xb[idx] - ob[s];
    f[1] = xb[NPTS + idx] - ob[NPOINT + s];
    f[2] = xb[2 * NPTS + idx] - ob[2 * NPOINT + s];
    f[3] = pb[idx];
    f[4] = pb[NPTS + idx];
    f[5] = pb[2 * NPTS + idx];
}

// ---------------------------------------------------------------------------
// P0: per-channel sums of y0 (lane = channel, rows looped, uniform loads)
// ---------------------------------------------------------------------------
__global__ __launch_bounds__(64) void stats0_kernel(const float* __restrict__ xyz,
                                                    const float* __restrict__ pts,
                                                    const float* __restrict__ outx,
                                                    const int* __restrict__ idxbuf,
                                                    const float* __restrict__ w0,
                                                    const float* __restrict__ b0,
                                                    float* __restrict__ stats)
{
    const int lane = threadIdx.x;
    float w[6];
#pragma unroll
    for (int c = 0; c < 6; ++c) w[c] = w0[lane * 6 + c];
    const float bb = b0[lane];
    float s = 0.f, q = 0.f;
    const int r0 = blockIdx.x * 128;
    for (int r = r0; r < r0 + 128; ++r) {
        int idx = idxbuf[r];
        float f[6];
        load_feats(xyz, pts, outx, r, idx, f);
        float y = bb;
#pragma unroll
        for (int c = 0; c < 6; ++c) y = fmaf(f[c], w[c], y);
        s += y;
        q = fmaf(y, y, q);
    }
    atomicAdd(&stats[lane], s);
    atomicAdd(&stats[64 + lane], q);
}

// ---------------------------------------------------------------------------
// BN param kernel: scale = g*rsqrt(var+eps); shift = be - mean*scale
// ---------------------------------------------------------------------------
__global__ void bnparam_kernel(const float* __restrict__ stats,
                               const float* __restrict__ g,
                               const float* __restrict__ be,
                               float* __restrict__ bn, int C)
{
    const int t = threadIdx.x;
    if (t >= C) return;
    const float inv = 1.0f / (float)NROWS;
    float mean = stats[t] * inv;
    float var = stats[C + t] * inv - mean * mean;
    float scale = g[t] * rsqrtf(var + 1e-5f);
    bn[t] = scale;
    bn[C + t] = be[t] - mean * scale;
}

// ---------------------------------------------------------------------------
// P1: 256 rows/block (4 waves). Weights staged in LDS (uniform float4
// broadcasts). y1 computed in 16-channel chunks into a per-wave padded tile;
// per-channel sum/sumsq via column reads + 2 shfl_xor steps.
// ---------------------------------------------------------------------------
#define TILE_W 65

__global__ __launch_bounds__(256, 2) void stats1_kernel(
    const float* __restrict__ xyz, const float* __restrict__ pts,
    const float* __restrict__ outx, const int* __restrict__ idxbuf,
    const float* __restrict__ w0, const float* __restrict__ b0,
    const float* __restrict__ bn0, const float* __restrict__ w1,
    const float* __restrict__ b1, float* __restrict__ stats)
{
    __shared__ __align__(16) float sw0[64 * 8];
    __shared__ __align__(16) float sw1[64 * 64];
    __shared__ float sb0[64];
    __shared__ float sb1[64];
    __shared__ float sbn0[128];
    __shared__ float tiles[4][16 * TILE_W];

    const int tid = threadIdx.x, lane = tid & 63, wid = tid >> 6;
    for (int i = tid; i < 64 * 64 / 4; i += 256)
        ((float4*)sw1)[i] = ((const float4*)w1)[i];
    for (int i = tid; i < 384; i += 256) sw0[(i / 6) * 8 + (i % 6)] = w0[i];
    if (tid < 64) { sb0[tid] = b0[tid]; sb1[tid] = b1[tid]; }
    if (tid < 128) sbn0[tid] = bn0[tid];
    __syncthreads();

    const int r = blockIdx.x * 256 + tid;
    const int idx = idxbuf[r];
    float f[6];
    load_feats(xyz, pts, outx, r, idx, f);

    float x1[64];
#pragma unroll
    for (int o = 0; o < 64; ++o) {
        const float4 wa = *(const float4*)&sw0[o * 8];
        const float2 wb = *(const float2*)&sw0[o * 8 + 4];
        float a = sb0[o];
        a = fmaf(f[0], wa.x, a); a = fmaf(f[1], wa.y, a);
        a = fmaf(f[2], wa.z, a); a = fmaf(f[3], wa.w, a);
        a = fmaf(f[4], wb.x, a); a = fmaf(f[5], wb.y, a);
        a = fmaf(a, sbn0[o], sbn0[64 + o]);
        x1[o] = fmaxf(a, 0.0f);
    }

    float* tile = tiles[wid];
    const int cc = lane & 15, rg = lane >> 4;
    const float* col = tile + cc * TILE_W + rg * 16;

#pragma unroll
    for (int h = 0; h < 4; ++h) {
        float y[16];
#pragma unroll
        for (int oi = 0; oi < 16; ++oi) {
            const int o = h * 16 + oi;
            float a = sb1[o];
            const float4* w4 = (const float4*)&sw1[o * 64];
#pragma unroll
            for (int c = 0; c < 16; ++c) {
                const float4 w = w4[c];
                a = fmaf(x1[4 * c + 0], w.x, a);
                a = fmaf(x1[4 * c + 1], w.y, a);
                a = fmaf(x1[4 * c + 2], w.z, a);
                a = fmaf(x1[4 * c + 3], w.w, a);
            }
            y[oi] = a;
        }
#pragma unroll
        for (int oi = 0; oi < 16; ++oi) tile[oi * TILE_W + lane] = y[oi];
        float s = 0.f, q = 0.f;
#pragma unroll
        for (int rr = 0; rr < 16; ++rr) {
            const float v = col[rr];
            s += v; q = fmaf(v, v, q);
        }
        s += __shfl_xor(s, 16); q += __shfl_xor(q, 16);
        s += __shfl_xor(s, 32); q += __shfl_xor(q, 32);
        if (lane < 16) {
            atomicAdd(&stats[h * 16 + cc], s);
            atomicAdd(&stats[64 + h * 16 + cc], q);
        }
    }
}

// ---------------------------------------------------------------------------
// P2: like P1 but through y2 (128 ch, 8 chunks); also per-32-row-group max
// (g>0 so relu∘bn2 monotone: max taken pre-bn2).
// ---------------------------------------------------------------------------
__global__ __launch_bounds__(256, 1) void stats2_kernel(
    const float* __restrict__ xyz, const float* __restrict__ pts,
    const float* __restrict__ outx, const int* __restrict__ idxbuf,
    const float* __restrict__ w0, const float* __restrict__ b0,
    const float* __restrict__ bn0, const float* __restrict__ w1,
    const float* __restrict__ b1, const float* __restrict__ bn1,
    const float* __restrict__ w2, const float* __restrict__ b2,
    float* __restrict__ stats, float* __restrict__ gmax)
{
    __shared__ __align__(16) float sw0[64 * 8];
    __shared__ __align__(16) float sw1[64 * 64];
    __shared__ __align__(16) float sw2[128 * 64];
    __shared__ float sb0[64];
    __shared__ float sb1[64];
    __shared__ float sb2[128];
    __shared__ float sbn0[128];
    __shared__ float sbn1[128];
    __shared__ float tiles[4][16 * TILE_W];

    const int tid = threadIdx.x, lane = tid & 63, wid = tid >> 6;
    for (int i = tid; i < 64 * 64 / 4; i += 256)
        ((float4*)sw1)[i] = ((const float4*)w1)[i];
    for (int i = tid; i < 128 * 64 / 4; i += 256)
        ((float4*)sw2)[i] = ((const float4*)w2)[i];
    for (int i = tid; i < 384; i += 256) sw0[(i / 6) * 8 + (i % 6)] = w0[i];
    if (tid < 64) { sb0[tid] = b0[tid]; sb1[tid] = b1[tid]; }
    if (tid < 128) { sb2[tid] = b2[tid]; sbn0[tid] = bn0[tid]; sbn1[tid] = bn1[tid]; }
    __syncthreads();

    const int r = blockIdx.x * 256 + tid;
    const int idx = idxbuf[r];
    float f[6];
    load_feats(xyz, pts, outx, r, idx, f);

    float x1[64];
#pragma unroll
    for (int o = 0; o < 64; ++o) {
        const float4 wa = *(const float4*)&sw0[o * 8];
        const float2 wb = *(const float2*)&sw0[o * 8 + 4];
        float a = sb0[o];
        a = fmaf(f[0], wa.x, a); a = fmaf(f[1], wa.y, a);
        a = fmaf(f[2], wa.z, a); a = fmaf(f[3], wa.w, a);
        a = fmaf(f[4], wb.x, a); a = fmaf(f[5], wb.y, a);
        a = fmaf(a, sbn0[o], sbn0[64 + o]);
        x1[o] = fmaxf(a, 0.0f);
    }

    float x2[64];
#pragma unroll
    for (int o = 0; o < 64; ++o) {
        float a = sb1[o];
        const float4* w4 = (const float4*)&sw1[o * 64];
#pragma unroll
        for (int c = 0; c < 16; ++c) {
            const float4 w = w4[c];
            a = fmaf(x1[4 * c + 0], w.x, a);
            a = fmaf(x1[4 * c + 1], w.y, a);
            a = fmaf(x1[4 * c + 2], w.z, a);
            a = fmaf(x1[4 * c + 3], w.w, a);
        }
        a = fmaf(a, sbn1[o], sbn1[64 + o]);
        x2[o] = fmaxf(a, 0.0f);
    }

    float* tile = tiles[wid];
    const int cc = lane & 15, rg = lane >> 4;
    const float* col = tile + cc * TILE_W + rg * 16;
    const int gA = blockIdx.x * 8 + wid * 2;

#pragma unroll
    for (int h = 0; h < 8; ++h) {
        float y[16];
#pragma unroll
        for (int oi = 0; oi < 16; ++oi) {
            const int o = h * 16 + oi;
            float a = sb2[o];
            const float4* w4 = (const float4*)&sw2[o * 64];
#pragma unroll
            for (int c = 0; c < 16; ++c) {
                const float4 w = w4[c];
                a = fmaf(x2[4 * c + 0], w.x, a);
                a = fmaf(x2[4 * c + 1], w.y, a);
                a = fmaf(x2[4 * c + 2], w.z, a);
                a = fmaf(x2[4 * c + 3], w.w, a);
            }
            y[oi] = a;
        }
#pragma unroll
        for (int oi = 0; oi < 16; ++oi) tile[oi * TILE_W + lane] = y[oi];
        float s = 0.f, q = 0.f, m = -3.0e38f;
#pragma unroll
        for (int rr = 0; rr < 16; ++rr) {
            const float v = col[rr];
            s += v; q = fmaf(v, v, q); m = fmaxf(m, v);
        }
        s += __shfl_xor(s, 16); q += __shfl_xor(q, 16);
        m = fmaxf(m, __shfl_xor(m, 16));
        s += __shfl_xor(s, 32); q += __shfl_xor(q, 32);
        const int ch = h * 16 + cc;
        if (lane < 16) {
            atomicAdd(&stats[ch], s);
            atomicAdd(&stats[128 + ch], q);
            gmax[ch * 8192 + gA] = m;
        } else if (lane >= 32 && lane < 48) {
            gmax[ch * 8192 + gA + 1] = m;
        }
    }
}

// ---------------------------------------------------------------------------
// P3: out2[b,o,s] = relu(bn2(gmax[o, b*1024+s]))
// ---------------------------------------------------------------------------
__global__ __launch_bounds__(256) void final_kernel(const float* __restrict__ gmax,
                                                    const float* __restrict__ bn2,
                                                    float* __restrict__ out2)
{
    const int t = blockIdx.x * 256 + threadIdx.x;
    const int s = t & 1023;
    const int o = (t >> 10) & 127;
    const int b = t >> 17;
    const int g = (b << 10) | s;
    float v = gmax[o * 8192 + g];
    v = fmaf(v, bn2[o], bn2[128 + o]);
    out2[t] = fmaxf(v, 0.0f);
}

// ---------------------------------------------------------------------------
extern "C" void kernel_launch(void* const* d_in, const int* in_sizes, int n_in,
                              void* d_out, int out_size, void* d_ws, size_t ws_size,
                              hipStream_t stream)
{
    const float* xyz = (const float*)d_in[0];
    const float* pts = (const float*)d_in[1];
    const float* w0  = (const float*)d_in[2];
    const float* b0  = (const float*)d_in[3];
    const float* g0  = (const float*)d_in[4];
    const float* be0 = (const float*)d_in[5];
    const float* w1  = (const float*)d_in[6];
    const float* b1  = (const float*)d_in[7];
    const float* g1  = (const float*)d_in[8];
    const float* be1 = (const float*)d_in[9];
    const float* w2  = (const float*)d_in[10];
    const float* b2  = (const float*)d_in[11];
    const float* g2  = (const float*)d_in[12];
    const float* be2 = (const float*)d_in[13];

    float* out_xyz = (float*)d_out;             // (B,3,1024) = 24576 floats
    float* out2    = out_xyz + 8 * 3 * NPOINT;  // (B,128,1024)

    char* wsb = (char*)d_ws;
    int*   idxbuf = (int*)(wsb + 32768);               // 262144 ints
    float* stats  = (float*)(wsb + 32768 + 1048576);   // 512 floats
    float* bnp    = stats + 512;                       // 512 floats
    float* gmax   = bnp + 512;                         // 128*8192 floats

    float* stats0 = stats;       float* stats1 = stats + 128; float* stats2 = stats + 256;
    float* bn0    = bnp;         float* bn1    = bnp + 128;   float* bn2    = bnp + 256;

    hipMemsetAsync(stats, 0, 512 * sizeof(float), stream);

    fps_kernel<<<8, 256, 0, stream>>>(xyz, out_xyz);
    ball_kernel<<<2048, 256, 0, stream>>>(xyz, out_xyz, idxbuf);
    stats0_kernel<<<2048, 64, 0, stream>>>(xyz, pts, out_xyz, idxbuf, w0, b0, stats0);
    bnparam_kernel<<<1, 64, 0, stream>>>(stats0, g0, be0, bn0, 64);
    stats1_kernel<<<1024, 256, 0, stream>>>(xyz, pts, out_xyz, idxbuf, w0, b0, bn0, w1, b1, stats1);
    bnparam_kernel<<<1, 64, 0, stream>>>(stats1, g1, be1, bn1, 64);
    stats2_kernel<<<1024, 256, 0, stream>>>(xyz, pts, out_xyz, idxbuf, w0, b0, bn0, w1, b1, bn1, w2, b2, stats2, gmax);
    bnparam_kernel<<<1, 128, 0, stream>>>(stats2, g2, be2, bn2, 128);
    final_kernel<<<4096, 256, 0, stream>>>(gmax, bn2, out2);
}

// Round 4
// 1196.529 us; speedup vs baseline: 1.2759x; 1.1497x over previous
//
#include <hip/hip_runtime.h>
#include <stdint.h>

#define NPTS   4096
#define NPOINT 1024
#define NSAMP  32
#define NROWS  262144   // B*NPOINT*NSAMP
#define RAD2   0.04f

typedef float v2f __attribute__((ext_vector_type(2)));

// ---------------------------------------------------------------------------
// FPS: one block per batch. Bit-exact distance chain vs fp32 reference
// (packed fp32 ops are IEEE-identical to scalar; contraction disabled).
// Argmax reduce: in-wave DPP (row_shr 1/2/4/8 + row_bcast 15/31) on
// (value, ~idx) 64-bit keys -> readlane(63) -> 4 wave keys in LDS -> ONE
// barrier -> all threads reduce 4 keys. Key slots parity double-buffered.
// ---------------------------------------------------------------------------
__global__ __launch_bounds__(256) void fps_kernel(const float* __restrict__ xyz,
                                                  float* __restrict__ outx)
{
    __shared__ __align__(16) float4 pxyz[NPTS];
    __shared__ __align__(16) unsigned long long wkey[2][4];
    const int b = blockIdx.x, tid = threadIdx.x;
    const int lane = tid & 63, wid = tid >> 6;
    const float* base = xyz + b * 3 * NPTS;

    float Xs[16], Ys[16], Zs[16];
#pragma unroll
    for (int j = 0; j < 16; ++j) {
        const int n = j * 256 + tid;
        Xs[j] = base[n];
        Ys[j] = base[NPTS + n];
        Zs[j] = base[2 * NPTS + n];
        pxyz[n] = make_float4(Xs[j], Ys[j], Zs[j], 0.0f);
    }
    v2f X2[8], Y2[8], Z2[8], D2[8];
#pragma unroll
    for (int j = 0; j < 8; ++j) {
        X2[j] = (v2f){Xs[2 * j], Xs[2 * j + 1]};
        Y2[j] = (v2f){Ys[2 * j], Ys[2 * j + 1]};
        Z2[j] = (v2f){Zs[2 * j], Zs[2 * j + 1]};
        D2[j] = (v2f){1e10f, 1e10f};
    }
    __syncthreads();
    float4 c4 = pxyz[0];
    float cx = c4.x, cy = c4.y, cz = c4.z;
    float* ox = outx + b * 3 * NPOINT;

    for (int t = 0; t < NPOINT; ++t) {
        if (tid == 0) {
            ox[t]              = cx;
            ox[NPOINT + t]     = cy;
            ox[2 * NPOINT + t] = cz;
        }
        const v2f cxv = (v2f){cx, cx}, cyv = (v2f){cy, cy}, czv = (v2f){cz, cz};
        float bv = -1.0f; int bi = 0;
#pragma unroll
        for (int j = 0; j < 8; ++j) {
            v2f nd;
            {
#pragma clang fp contract(off)
                const v2f dx = X2[j] - cxv;
                const v2f dy = Y2[j] - cyv;
                const v2f dz = Z2[j] - czv;
                const v2f m0 = dx * dx;
                const v2f m1 = dy * dy;
                const v2f m2 = dz * dz;
                const v2f d = (m0 + m1) + m2;
                nd = __builtin_elementwise_min(D2[j], d);
            }
            D2[j] = nd;
            if (nd.x > bv) { bv = nd.x; bi = j * 512 + tid; }
            if (nd.y > bv) { bv = nd.y; bi = j * 512 + 256 + tid; }
        }
        // (value, ~idx) key; u64-lexicographic max == (max value, min idx)
        unsigned kv = __float_as_uint(bv);      // bv >= 0 -> monotone as uint
        unsigned ki = ~(unsigned)bi;
#define DPP_STEP(C)                                                            \
        {                                                                      \
            unsigned ov = (unsigned)__builtin_amdgcn_update_dpp(               \
                0, (int)kv, C, 0xf, 0xf, true);                                \
            unsigned oi = (unsigned)__builtin_amdgcn_update_dpp(               \
                0, (int)ki, C, 0xf, 0xf, true);                                \
            bool g = (ov > kv) || (ov == kv && oi > ki);                       \
            kv = g ? ov : kv;                                                  \
            ki = g ? oi : ki;                                                  \
        }
        DPP_STEP(0x111)   // row_shr:1
        DPP_STEP(0x112)   // row_shr:2
        DPP_STEP(0x114)   // row_shr:4
        DPP_STEP(0x118)   // row_shr:8
        DPP_STEP(0x142)   // row_bcast:15
        DPP_STEP(0x143)   // row_bcast:31
#undef DPP_STEP
        const unsigned wv = (unsigned)__builtin_amdgcn_readlane((int)kv, 63);
        const unsigned wi = (unsigned)__builtin_amdgcn_readlane((int)ki, 63);
        if (lane == 0)
            wkey[t & 1][wid] = ((unsigned long long)wv << 32) | wi;
        __syncthreads();
        const ulonglong2* wk = (const ulonglong2*)wkey[t & 1];
        ulonglong2 ka = wk[0], kb = wk[1];
        unsigned long long kk = ka.x;
        if (ka.y > kk) kk = ka.y;
        if (kb.x > kk) kk = kb.x;
        if (kb.y > kk) kk = kb.y;
        const int farthest = (int)(~(unsigned int)kk) & (NPTS - 1);
        c4 = pxyz[farthest];
        cx = c4.x; cy = c4.y; cz = c4.z;
    }
}

// ---------------------------------------------------------------------------
// Ball query: one wave per query; first 32 in-radius indices in ascending order
// ---------------------------------------------------------------------------
__global__ __launch_bounds__(256) void ball_kernel(const float* __restrict__ xyz,
                                                   const float* __restrict__ outx,
                                                   int* __restrict__ idxbuf)
{
    const int w = blockIdx.x * 4 + (threadIdx.x >> 6);
    const int lane = threadIdx.x & 63;
    const int b = w >> 10, s = w & 1023;
    const float* base = xyz + b * 3 * NPTS;
    const float cx = outx[b * 3 * NPOINT + s];
    const float cy = outx[b * 3 * NPOINT + NPOINT + s];
    const float cz = outx[b * 3 * NPOINT + 2 * NPOINT + s];
    const float sumS = __fadd_rn(__fadd_rn(__fmul_rn(cx, cx), __fmul_rn(cy, cy)),
                                 __fmul_rn(cz, cz));
    int cnt = 0, first_n = -1;
    int* myidx = idxbuf + w * NSAMP;

    for (int chunk = 0; chunk < NPTS / 64 && cnt < NSAMP; ++chunk) {
        const int n = chunk * 64 + lane;
        float nx = base[n], ny = base[NPTS + n], nz = base[2 * NPTS + n];
        float sumN = __fadd_rn(__fadd_rn(__fmul_rn(nx, nx), __fmul_rn(ny, ny)),
                               __fmul_rn(nz, nz));
        float dot = __fadd_rn(__fadd_rn(__fmul_rn(cx, nx), __fmul_rn(cy, ny)),
                              __fmul_rn(cz, nz));
        float sq = __fsub_rn(__fadd_rn(sumS, sumN), __fmul_rn(2.0f, dot));
        bool keep = (sq <= RAD2);
        unsigned long long mask = __ballot(keep);
        if (first_n < 0 && mask) first_n = chunk * 64 + (int)__builtin_ctzll(mask);
        int pos = cnt + __popcll(mask & ((1ull << lane) - 1ull));
        if (keep && pos < NSAMP) myidx[pos] = n;
        cnt += __popcll(mask);
    }
    if (cnt < NSAMP) {
        if (lane >= cnt && lane < NSAMP) myidx[lane] = first_n;
    }
}

// ---------------------------------------------------------------------------
// helpers
// ---------------------------------------------------------------------------
__device__ __forceinline__ void load_feats(const float* __restrict__ xyz,
                                           const float* __restrict__ pts,
                                           const float* __restrict__ outx,
                                           int r, int idx, float f[6])
{
    const int b = r >> 15;
    const int s = (r >> 5) & 1023;
    const float* xb = xyz + b * 3 * NPTS;
    const float* pb = pts + b * 3 * NPTS;
    const float* ob = outx + b * 3 * NPOINT;
    f[0] = xb[idx] - ob[s];
    f[1] = xb[NPTS + idx] - ob[NPOINT + s];
    f[2] = xb[2 * NPTS + idx] - ob[2 * NPOINT + s];
    f[3] = pb[idx];
    f[4] = pb[NPTS + idx];
    f[5] = pb[2 * NPTS + idx];
}

// ---------------------------------------------------------------------------
// P0: per-channel sums of y0 (lane = channel, rows looped, uniform loads)
// ---------------------------------------------------------------------------
__global__ __launch_bounds__(64) void stats0_kernel(const float* __restrict__ xyz,
                                                    const float* __restrict__ pts,
                                                    const float* __restrict__ outx,
                                                    const int* __restrict__ idxbuf,
                                                    const float* __restrict__ w0,
                                                    const float* __restrict__ b0,
                                                    float* __restrict__ stats)
{
    const int lane = threadIdx.x;
    float w[6];
#pragma unroll
    for (int c = 0; c < 6; ++c) w[c] = w0[lane * 6 + c];
    const float bb = b0[lane];
    float s = 0.f, q = 0.f;
    const int r0 = blockIdx.x * 128;
    for (int r = r0; r < r0 + 128; ++r) {
        int idx = idxbuf[r];
        float f[6];
        load_feats(xyz, pts, outx, r, idx, f);
        float y = bb;
#pragma unroll
        for (int c = 0; c < 6; ++c) y = fmaf(f[c], w[c], y);
        s += y;
        q = fmaf(y, y, q);
    }
    atomicAdd(&stats[lane], s);
    atomicAdd(&stats[64 + lane], q);
}

// ---------------------------------------------------------------------------
// BN param kernel: scale = g*rsqrt(var+eps); shift = be - mean*scale
// ---------------------------------------------------------------------------
__global__ void bnparam_kernel(const float* __restrict__ stats,
                               const float* __restrict__ g,
                               const float* __restrict__ be,
                               float* __restrict__ bn, int C)
{
    const int t = threadIdx.x;
    if (t >= C) return;
    const float inv = 1.0f / (float)NROWS;
    float mean = stats[t] * inv;
    float var = stats[C + t] * inv - mean * mean;
    float scale = g[t] * rsqrtf(var + 1e-5f);
    bn[t] = scale;
    bn[C + t] = be[t] - mean * scale;
}

// ---------------------------------------------------------------------------
// x1 for a row pair (packed). Weights read with loop-uniform indices ->
// scalar (s_load) broadcasts feeding v_pk_fma.
// ---------------------------------------------------------------------------
__device__ __forceinline__ void compute_x1_pair(const v2f fp[6],
                                                const float* __restrict__ w0,
                                                const float* __restrict__ b0,
                                                const float* __restrict__ bn0,
                                                v2f x1[64])
{
#pragma unroll
    for (int o = 0; o < 64; ++o) {
        v2f a = (v2f){b0[o], b0[o]};
#pragma unroll
        for (int c = 0; c < 6; ++c) a += fp[c] * w0[o * 6 + c];
        a = a * bn0[o] + (v2f){bn0[64 + o], bn0[64 + o]};
        x1[o] = __builtin_elementwise_max(a, (v2f){0.0f, 0.0f});
    }
}

// ---------------------------------------------------------------------------
// P1: 512 rows/block (2 rows/thread, packed fp32). Weights from global
// (uniform -> scalar cache). y1 chunks through per-wave LDS tile for the
// row->channel transpose; sums via shfl_xor.
// ---------------------------------------------------------------------------
__global__ __launch_bounds__(256, 1) void stats1_kernel(
    const float* __restrict__ xyz, const float* __restrict__ pts,
    const float* __restrict__ outx, const int* __restrict__ idxbuf,
    const float* __restrict__ w0, const float* __restrict__ b0,
    const float* __restrict__ bn0, const float* __restrict__ w1,
    const float* __restrict__ b1, float* __restrict__ stats)
{
    __shared__ float2 tiles[4][16 * 65];
    const int tid = threadIdx.x, lane = tid & 63, wid = tid >> 6;
    const int rA = blockIdx.x * 512 + tid;
    const int rB = rA + 256;
    const int iA = idxbuf[rA], iB = idxbuf[rB];
    float fA[6], fB[6];
    load_feats(xyz, pts, outx, rA, iA, fA);
    load_feats(xyz, pts, outx, rB, iB, fB);
    v2f fp[6];
#pragma unroll
    for (int c = 0; c < 6; ++c) fp[c] = (v2f){fA[c], fB[c]};

    v2f x1[64];
    compute_x1_pair(fp, w0, b0, bn0, x1);

    float2* tile = tiles[wid];
    const int ch = lane & 15, seg = lane >> 4;
    const float2* col = tile + ch * 65 + seg * 16;

#pragma unroll
    for (int h = 0; h < 4; ++h) {
#pragma unroll
        for (int oi = 0; oi < 16; ++oi) {
            const int o = h * 16 + oi;
            v2f a = (v2f){b1[o], b1[o]};
#pragma unroll
            for (int c = 0; c < 64; ++c) a += x1[c] * w1[o * 64 + c];
            tile[oi * 65 + lane] = make_float2(a.x, a.y);
        }
        v2f s = (v2f){0.f, 0.f}, q = (v2f){0.f, 0.f};
#pragma unroll
        for (int k = 0; k < 16; ++k) {
            const float2 vv = col[k];
            const v2f v = (v2f){vv.x, vv.y};
            s += v; q += v * v;
        }
        float ss = s.x + s.y, qq = q.x + q.y;
        ss += __shfl_xor(ss, 16); qq += __shfl_xor(qq, 16);
        ss += __shfl_xor(ss, 32); qq += __shfl_xor(qq, 32);
        if (lane < 16) {
            atomicAdd(&stats[h * 16 + ch], ss);
            atomicAdd(&stats[64 + h * 16 + ch], qq);
        }
    }
}

// ---------------------------------------------------------------------------
// P2: like P1 through y2 (128 ch, 8 chunks) + per-32-row-group max
// (g>0 so relu∘bn2 monotone: max taken pre-bn2).
// Row pair (rA, rB=rA+256): rA rows land in groups 2w(+1), rB in 2w+8(+9).
// ---------------------------------------------------------------------------
__global__ __launch_bounds__(256, 1) void stats2_kernel(
    const float* __restrict__ xyz, const float* __restrict__ pts,
    const float* __restrict__ outx, const int* __restrict__ idxbuf,
    const float* __restrict__ w0, const float* __restrict__ b0,
    const float* __restrict__ bn0, const float* __restrict__ w1,
    const float* __restrict__ b1, const float* __restrict__ bn1,
    const float* __restrict__ w2, const float* __restrict__ b2,
    float* __restrict__ stats, float* __restrict__ gmax)
{
    __shared__ float2 tiles[4][16 * 65];
    const int tid = threadIdx.x, lane = tid & 63, wid = tid >> 6;
    const int rA = blockIdx.x * 512 + tid;
    const int rB = rA + 256;
    const int iA = idxbuf[rA], iB = idxbuf[rB];
    float fA[6], fB[6];
    load_feats(xyz, pts, outx, rA, iA, fA);
    load_feats(xyz, pts, outx, rB, iB, fB);
    v2f fp[6];
#pragma unroll
    for (int c = 0; c < 6; ++c) fp[c] = (v2f){fA[c], fB[c]};

    v2f x1[64];
    compute_x1_pair(fp, w0, b0, bn0, x1);

    v2f x2[64];
#pragma unroll
    for (int o = 0; o < 64; ++o) {
        v2f a = (v2f){b1[o], b1[o]};
#pragma unroll
        for (int c = 0; c < 64; ++c) a += x1[c] * w1[o * 64 + c];
        a = a * bn1[o] + (v2f){bn1[64 + o], bn1[64 + o]};
        x2[o] = __builtin_elementwise_max(a, (v2f){0.0f, 0.0f});
    }

    float2* tile = tiles[wid];
    const int ch = lane & 15, seg = lane >> 4;
    const float2* col = tile + ch * 65 + seg * 16;
    const int G = blockIdx.x * 16;

#pragma unroll
    for (int h = 0; h < 8; ++h) {
#pragma unroll
        for (int oi = 0; oi < 16; ++oi) {
            const int o = h * 16 + oi;
            v2f a = (v2f){b2[o], b2[o]};
#pragma unroll
            for (int c = 0; c < 64; ++c) a += x2[c] * w2[o * 64 + c];
            tile[oi * 65 + lane] = make_float2(a.x, a.y);
        }
        v2f s = (v2f){0.f, 0.f}, q = (v2f){0.f, 0.f};
        float mA = -3.0e38f, mB = -3.0e38f;
#pragma unroll
        for (int k = 0; k < 16; ++k) {
            const float2 vv = col[k];
            const v2f v = (v2f){vv.x, vv.y};
            s += v; q += v * v;
            mA = fmaxf(mA, vv.x); mB = fmaxf(mB, vv.y);
        }
        float ss = s.x + s.y, qq = q.x + q.y;
        ss += __shfl_xor(ss, 16); qq += __shfl_xor(qq, 16);
        mA = fmaxf(mA, __shfl_xor(mA, 16));
        mB = fmaxf(mB, __shfl_xor(mB, 16));
        ss += __shfl_xor(ss, 32); qq += __shfl_xor(qq, 32);
        const int o = h * 16 + ch;
        if (lane < 16) {
            atomicAdd(&stats[o], ss);
            atomicAdd(&stats[128 + o], qq);
            gmax[o * 8192 + G + 2 * wid]     = mA;   // group of rA, segs 0-1
            gmax[o * 8192 + G + 2 * wid + 8] = mB;   // group of rB
        } else if (lane >= 32 && lane < 48) {
            gmax[o * 8192 + G + 2 * wid + 1] = mA;   // group of rA, segs 2-3
            gmax[o * 8192 + G + 2 * wid + 9] = mB;
        }
    }
}

// ---------------------------------------------------------------------------
// P3: out2[b,o,s] = relu(bn2(gmax[o, b*1024+s]))
// ---------------------------------------------------------------------------
__global__ __launch_bounds__(256) void final_kernel(const float* __restrict__ gmax,
                                                    const float* __restrict__ bn2,
                                                    float* __restrict__ out2)
{
    const int t = blockIdx.x * 256 + threadIdx.x;
    const int s = t & 1023;
    const int o = (t >> 10) & 127;
    const int b = t >> 17;
    const int g = (b << 10) | s;
    float v = gmax[o * 8192 + g];
    v = fmaf(v, bn2[o], bn2[128 + o]);
    out2[t] = fmaxf(v, 0.0f);
}

// ---------------------------------------------------------------------------
extern "C" void kernel_launch(void* const* d_in, const int* in_sizes, int n_in,
                              void* d_out, int out_size, void* d_ws, size_t ws_size,
                              hipStream_t stream)
{
    const float* xyz = (const float*)d_in[0];
    const float* pts = (const float*)d_in[1];
    const float* w0  = (const float*)d_in[2];
    const float* b0  = (const float*)d_in[3];
    const float* g0  = (const float*)d_in[4];
    const float* be0 = (const float*)d_in[5];
    const float* w1  = (const float*)d_in[6];
    const float* b1  = (const float*)d_in[7];
    const float* g1  = (const float*)d_in[8];
    const float* be1 = (const float*)d_in[9];
    const float* w2  = (const float*)d_in[10];
    const float* b2  = (const float*)d_in[11];
    const float* g2  = (const float*)d_in[12];
    const float* be2 = (const float*)d_in[13];

    float* out_xyz = (float*)d_out;             // (B,3,1024) = 24576 floats
    float* out2    = out_xyz + 8 * 3 * NPOINT;  // (B,128,1024)

    char* wsb = (char*)d_ws;
    int*   idxbuf = (int*)(wsb + 32768);               // 262144 ints
    float* stats  = (float*)(wsb + 32768 + 1048576);   // 512 floats
    float* bnp    = stats + 512;                       // 512 floats
    float* gmax   = bnp + 512;                         // 128*8192 floats

    float* stats0 = stats;       float* stats1 = stats + 128; float* stats2 = stats + 256;
    float* bn0    = bnp;         float* bn1    = bnp + 128;   float* bn2    = bnp + 256;

    hipMemsetAsync(stats, 0, 512 * sizeof(float), stream);

    fps_kernel<<<8, 256, 0, stream>>>(xyz, out_xyz);
    ball_kernel<<<2048, 256, 0, stream>>>(xyz, out_xyz, idxbuf);
    stats0_kernel<<<2048, 64, 0, stream>>>(xyz, pts, out_xyz, idxbuf, w0, b0, stats0);
    bnparam_kernel<<<1, 64, 0, stream>>>(stats0, g0, be0, bn0, 64);
    stats1_kernel<<<512, 256, 0, stream>>>(xyz, pts, out_xyz, idxbuf, w0, b0, bn0, w1, b1, stats1);
    bnparam_kernel<<<1, 64, 0, stream>>>(stats1, g1, be1, bn1, 64);
    stats2_kernel<<<512, 256, 0, stream>>>(xyz, pts, out_xyz, idxbuf, w0, b0, bn0, w1, b1, bn1, w2, b2, stats2, gmax);
    bnparam_kernel<<<1, 128, 0, stream>>>(stats2, g2, be2, bn2, 128);
    final_kernel<<<4096, 256, 0, stream>>>(gmax, bn2, out2);
}